// Round 7
// baseline (435.340 us; speedup 1.0000x reference)
//
#include <hip/hip_runtime.h>
#include <hip/hip_fp16.h>

typedef _Float16 f16;
typedef _Float16 f16x8 __attribute__((ext_vector_type(8)));
typedef float f32x4 __attribute__((ext_vector_type(4)));

#define NB 512
#define NL 16
#define NK 10000
#define NH 128
#define NSTEP 313  // ceil(10000/32), zero-padded K

__device__ __forceinline__ float fast_exp2(float x) {
#if __has_builtin(__builtin_amdgcn_exp2f)
  return __builtin_amdgcn_exp2f(x);
#else
  return exp2f(x);
#endif
}
__device__ __forceinline__ float fast_rcp(float x) {
#if __has_builtin(__builtin_amdgcn_rcpf)
  return __builtin_amdgcn_rcpf(x);
#else
  return 1.f / x;
#endif
}
__device__ __forceinline__ float sigf(float x) {
  return fast_rcp(1.f + fast_exp2(-1.44269504f * x));
}
__device__ __forceinline__ float tanh_fast(float x) {
  return 2.f * fast_rcp(1.f + fast_exp2(-2.88539008f * x)) - 1.f;
}

__device__ __forceinline__ void gload16(const void* g, void* l) {
  __builtin_amdgcn_global_load_lds(
      (const __attribute__((address_space(1))) unsigned int*)g,
      (__attribute__((address_space(3))) unsigned int*)l, 16, 0, 0);
}

// ---------------------------------------------------------------- prep ------
// Wf: B in MFMA-fragment order: [s][nt][lane][e] with lane=(kg*16+lr),
// value = Wnode[col=nt*16+lr][k=s*32+kg*8+e], zero-padded past K=10000.
__global__ void prep_kernel(
    const float* __restrict__ x, const float* __restrict__ t0,
    const float* __restrict__ tau, const float* __restrict__ endi,
    const float* __restrict__ coords,
    const float* __restrict__ Wx1, const float* __restrict__ Wx2,
    const float* __restrict__ bx2, const float* __restrict__ Wres,
    const float* __restrict__ bres, const float* __restrict__ Wnode,
    const float* __restrict__ Wtau, const float* __restrict__ btau,
    const float* __restrict__ Wend1, const float* __restrict__ Wend2,
    const float* __restrict__ bend2, const float* __restrict__ Wcoord,
    const float* __restrict__ Wih, const float* __restrict__ Whh,
    const float* __restrict__ bih, const float* __restrict__ bhh,
    f16* __restrict__ xh, f16* __restrict__ t0h, f16* __restrict__ endh,
    f16* __restrict__ tauh, f16* __restrict__ coordh, f16* __restrict__ Wf,
    f16* __restrict__ Wih16, f16* __restrict__ Whh16, float* __restrict__ bsum) {
  const int tid0 = blockIdx.x * blockDim.x + threadIdx.x;
  const int stride = gridDim.x * blockDim.x;

  const int nWf = NSTEP * 4096;     // 1,282,048
  const int nW = 7 * 512 * NH;      // 458,752
  const int nb = 7 * 512;
  const int nxh = NB * NH;          // 65,536
  const int ntau = NB * NL * NH;    // 1,048,576
  const int nco = NB * 2 * NL * NH; // 2,097,152

  for (int i = tid0; i < nWf; i += stride) {
    const int s = i >> 12, r = i & 4095;
    const int nt = r >> 9, l2 = r & 511;
    const int lane = l2 >> 3, e = l2 & 7;
    const int kg = lane >> 4, lr = lane & 15;
    const int col = nt * 16 + lr;
    const int k = s * 32 + kg * 8 + e;
    Wf[i] = (k < NK) ? (f16)Wnode[(size_t)col * NK + k] : (f16)0.f;
  }
  for (int i = tid0; i < nW; i += stride) {
    Wih16[i] = (f16)Wih[i];
    Whh16[i] = (f16)Whh[i];
  }
  for (int i = tid0; i < nb; i += stride) bsum[i] = bih[i] + bhh[i];
  for (int i = tid0; i < nxh; i += stride) {
    const int b = i >> 7, h = i & 127;
    const float s = x[2 * b] * Wx1[0] + x[2 * b + 1] * Wx1[1];
    xh[i] = (f16)tanhf(s * Wx2[h] + bx2[h]);
    t0h[i] = (f16)tanhf(t0[b] * Wres[h] + bres[h]);
    const float e = endi[2 * b] * Wend1[0] + endi[2 * b + 1] * Wend1[1];
    endh[i] = (f16)(e * Wend2[h] + bend2[h]);
  }
  for (int i = tid0; i < ntau; i += stride) {
    const int h = i & 127, bl = i >> 7;
    tauh[i] = (f16)tanhf(tau[bl] * Wtau[h] + btau[h]);
  }
  for (int i = tid0; i < nco; i += stride) {
    const int h = i & 127, br = i >> 7;
    coordh[i] = (f16)(coords[2 * br] * Wcoord[2 * h] +
                      coords[2 * br + 1] * Wcoord[2 * h + 1]);
  }
}

// ------------------------------------------------------------ node GEMM -----
// C(16384x128,f16) = A(16384x10000,f32) * W^T.  Grid 256 wgs (1/CU), each
// owns 64 rows x full K. Per K-step tile: A 64x32 f32 (8 KB, XOR-row-swizzled
// via pre-swizzled source) + B fragments (8 KB) both staged by
// global_load_lds into a 3-deep LDS ring. Counted s_waitcnt vmcnt(2) keeps
// one full tile permanently in flight (never drains); raw s_barrier.
// Wave w: rows (w&3)*16..+16, cols ((w>>2)*4)*16..+64.
__global__ __launch_bounds__(512, 2) void node_gemm(const float* __restrict__ A,
                                                    const f16* __restrict__ Wf,
                                                    f16* __restrict__ Cn) {
  __shared__ char lds[3][16384];  // per buf: [0,8K) A tile | [8K,16K) B tile
  const int tid = threadIdx.x;
  const int w = tid >> 6, l = tid & 63;
  const int lr = l & 15, kg = l >> 4;
  const int r0 = blockIdx.x * 64;

  // ---- staging addresses ----
  // A: wave w stages rows w*8..w*8+8 (8 lanes x 16 B per row-chunk of 128 B)
  const int srow = w * 8 + (l >> 3);
  const int swz = ((l & 7) * 16) ^ ((srow & 7) << 4);
  const char* asrc = (const char*)A + (size_t)(r0 + srow) * 40000 + swz;
  const int bndA = 39984 - swz;  // clamp keeps 16B in-bounds; Wf pad zeros it
  // B: thread tid stages Wf[t*4096 + tid*8 .. +8]
  const char* bsrc = (const char*)Wf + (size_t)tid * 16;

  // ---- compute assignment ----
  const int rs = w & 3;          // 16-row subtile
  const int nt0 = (w >> 2) * 4;  // col-tile base
  int rdoA[2];
#pragma unroll
  for (int h = 0; h < 2; h++) {
    const int row = rs * 16 + lr;
    rdoA[h] = row * 128 + ((kg * 32 + h * 16) ^ ((row & 7) << 4));
  }

  f32x4 acc[4];
#pragma unroll
  for (int j = 0; j < 4; j++) {
    f32x4 z = {0.f, 0.f, 0.f, 0.f};
    acc[j] = z;
  }

  auto stage = [&](int t, char* buf) {
    const int tb = t * 128;
    const int off = tb < bndA ? tb : bndA;
    gload16(asrc + off, buf + w * 1024);                       // A
    gload16(bsrc + (size_t)t * 8192, buf + 8192 + w * 1024);   // B
  };

  char* b0 = &lds[0][0];
  char* b1 = &lds[1][0];
  char* b2 = &lds[2][0];

  stage(0, b0);
  stage(1, b1);

  char* bufs[3] = {b0, b1, b2};
  int cur = 0;
  for (int t = 0; t < NSTEP; t++) {
    if (t + 1 < NSTEP) {
      asm volatile("s_waitcnt vmcnt(2)" ::: "memory");  // stage(t) landed
    } else {
      asm volatile("s_waitcnt vmcnt(0)" ::: "memory");
    }
    __builtin_amdgcn_s_barrier();
    // overwrite slot (t+2)%3 = the buffer read two iters ago (reads retired)
    if (t + 2 < NSTEP) stage(t + 2, bufs[cur == 0 ? 2 : cur - 1]);

    const char* cb = bufs[cur];
    // A fragment (8 k-values = 32 B, two swizzled b128 reads)
    const f32x4 a0 = *(const f32x4*)(cb + rdoA[0]);
    const f32x4 a1 = *(const f32x4*)(cb + rdoA[1]);
    f16x8 af;
    af[0] = (f16)a0[0]; af[1] = (f16)a0[1]; af[2] = (f16)a0[2]; af[3] = (f16)a0[3];
    af[4] = (f16)a1[0]; af[5] = (f16)a1[1]; af[6] = (f16)a1[2]; af[7] = (f16)a1[3];
    // B fragments for this wave's 4 col-tiles
    const char* bb = cb + 8192 + l * 16;
#pragma unroll
    for (int j = 0; j < 4; j++) {
      const f16x8 bv = *(const f16x8*)(bb + (nt0 + j) * 1024);
      acc[j] = __builtin_amdgcn_mfma_f32_16x16x32_f16(af, bv, acc[j], 0, 0, 0);
    }
    cur = (cur == 2) ? 0 : cur + 1;
  }

  // C write: row=(lane>>4)*4+reg, col=lane&15 within each 16x16 tile
  f16* crow = Cn + (size_t)(r0 + rs * 16 + kg * 4) * NH + nt0 * 16 + lr;
#pragma unroll
  for (int j = 0; j < 4; j++)
#pragma unroll
    for (int jr = 0; jr < 4; jr++)
      crow[(size_t)jr * NH + j * 16] = (f16)acc[j][jr];
}

// --------------------------------------------------------------- LSTM -------
// grid: 7 k's x 32 batch-chunks of 16. One wg = 8 waves (512 thr); wave w
// owns hidden units [w*16, w*16+16) across all four gates (4 gate-tiles).
// Wih/Whh fragments in VGPRs (~128), x prefetched 1 step ahead. x-MFMAs run
// before h-MFMAs so the ds_read(h) latency hides under them.
__global__ __launch_bounds__(512, 2) void lstm_run(
    const f16* __restrict__ xh, const f16* __restrict__ t0h,
    const f16* __restrict__ endh, const f16* __restrict__ tauh,
    const f16* __restrict__ nodeh, const f16* __restrict__ coordh,
    const f16* __restrict__ Wih16, const f16* __restrict__ Whh16,
    const float* __restrict__ bsum, const float* __restrict__ hW1,
    const float* __restrict__ hb1, const float* __restrict__ hW2,
    const float* __restrict__ hb2, float* __restrict__ out) {
  __shared__ f16 hbuf[2][16 * NH];  // double-buffered h, XOR-swizzled bytes
  __shared__ float hu[16 * NH];

  const int k = blockIdx.x >> 5;
  const int b0 = (blockIdx.x & 31) << 4;
  const int w = threadIdx.x >> 6;
  const int l = threadIdx.x & 63;
  const int lr = l & 15, kg = l >> 4;

  int len;
  switch (k) {
    case 0: len = 83; break;
    case 1: len = 19; break;
    case 2: len = 32; break;
    case 3: len = 32; break;
    case 4: len = 51; break;
    case 5: len = 64; break;
    default: len = 51; break;
  }

  // per-step input fragment pointer (wave-uniform select logic)
  auto xptr = [&](int t) -> const f16* {
    const f16* cb; int bstr, idx;
    if (k == 2) { cb = nodeh; bstr = 32 * NH; idx = t; }
    else if (k == 3) { cb = coordh; bstr = 32 * NH; idx = t; }
    else if (k == 5) {
      const int q = t >> 2, r = t & 3;
      cb = (r == 0 || r == 2) ? nodeh : coordh;
      bstr = 32 * NH;
      idx = 2 * q + ((r >= 2) ? 1 : 0);
    } else {
      if (t == 0) { cb = xh; bstr = NH; idx = 0; }
      else if (t == 1) { cb = t0h; bstr = NH; idx = 0; }
      else if (t == len - 1) { cb = endh; bstr = NH; idx = 0; }
      else {
        const int u = t - 2;
        if (k == 0) {
          const int q = u / 5, r = u - 5 * q;
          if (r == 0) { cb = tauh; bstr = 16 * NH; idx = q; }
          else if (r == 1) { cb = nodeh; bstr = 32 * NH; idx = 2 * q; }
          else if (r == 2) { cb = coordh; bstr = 32 * NH; idx = 2 * q; }
          else if (r == 3) { cb = nodeh; bstr = 32 * NH; idx = 2 * q + 1; }
          else { cb = coordh; bstr = 32 * NH; idx = 2 * q + 1; }
        } else if (k == 1) { cb = tauh; bstr = 16 * NH; idx = u; }
        else if (k == 4) {
          const int q = u / 3, r = u - 3 * q;
          if (r == 0) { cb = tauh; bstr = 16 * NH; idx = q; }
          else { cb = nodeh; bstr = 32 * NH; idx = 2 * q + (r - 1); }
        } else {  // k == 6
          const int q = u / 3, r = u - 3 * q;
          if (r == 0) { cb = tauh; bstr = 16 * NH; idx = q; }
          else { cb = coordh; bstr = 32 * NH; idx = 2 * q + (r - 1); }
        }
      }
    }
    return cb + (size_t)(b0 + lr) * bstr + idx * NH + kg * 8;
  };

  // ---- load weight fragments into registers ----
  // wave w owns hidden cols [w*16, w*16+16); gate g's row block = g*128.
  f16x8 Wh[4][4], Wi[4][4];
  float bias[4];
  {
    const f16* whb = Whh16 + (size_t)k * 512 * NH;
    const f16* wib = Wih16 + (size_t)k * 512 * NH;
#pragma unroll
    for (int g = 0; g < 4; g++) {
      const int col = g * 128 + w * 16 + lr;
      bias[g] = bsum[k * 512 + col];
#pragma unroll
      for (int kc = 0; kc < 4; kc++) {
        Wh[kc][g] = *(const f16x8*)(whb + (size_t)col * NH + kc * 32 + kg * 8);
        Wi[kc][g] = *(const f16x8*)(wib + (size_t)col * NH + kc * 32 + kg * 8);
      }
    }
  }

  char* lds0 = (char*)&hbuf[0][0];
  // zero h buffer 0 (h0 = 0): 512 threads x 8 B = 4096 B
  *(unsigned long long*)(lds0 + threadIdx.x * 8) = 0ull;
  __syncthreads();

  float c[4] = {0, 0, 0, 0};

  // precomputed swizzled LDS byte offsets (constant across t)
  int rdo[4];
#pragma unroll
  for (int kc = 0; kc < 4; kc++) {
    const int colb = (kc * 32 + kg * 8) * 2;
    rdo[kc] = lr * 256 + (colb ^ ((lr & 7) << 4));
  }
  int wro[4];
#pragma unroll
  for (int jr = 0; jr < 4; jr++) {
    const int hrow = kg * 4 + jr;
    const int hcol = w * 16 + lr;
    wro[jr] = hrow * 256 + ((hcol * 2) ^ ((hrow & 7) << 4));
  }

  // prime x for t=0
  f16x8 axc[4];
  {
    const f16* xp = xptr(0);
#pragma unroll
    for (int kc = 0; kc < 4; kc++) axc[kc] = *(const f16x8*)(xp + kc * 32);
  }

  int cur = 0;
  for (int t = 0; t < len; t++) {
    char* rb = lds0 + cur * 4096;
    f16x8 ah[4];
#pragma unroll
    for (int kc = 0; kc < 4; kc++) ah[kc] = *(const f16x8*)(rb + rdo[kc]);

    // prefetch next-step x into registers (hidden under MFMA+gates+barrier)
    f16x8 axn[4];
    if (t + 1 < len) {
      const f16* xp = xptr(t + 1);
#pragma unroll
      for (int kc = 0; kc < 4; kc++) axn[kc] = *(const f16x8*)(xp + kc * 32);
    }

    f32x4 acc[4];
#pragma unroll
    for (int g = 0; g < 4; g++) {
      f32x4 binit = {bias[g], bias[g], bias[g], bias[g]};
      acc[g] = binit;
    }
    // x-part first (register operands ready) -> hides ds_read(h) latency
#pragma unroll
    for (int kc = 0; kc < 4; kc++)
#pragma unroll
      for (int g = 0; g < 4; g++)
        acc[g] = __builtin_amdgcn_mfma_f32_16x16x32_f16(axc[kc], Wi[kc][g], acc[g], 0, 0, 0);
#pragma unroll
    for (int kc = 0; kc < 4; kc++)
#pragma unroll
      for (int g = 0; g < 4; g++)
        acc[g] = __builtin_amdgcn_mfma_f32_16x16x32_f16(ah[kc], Wh[kc][g], acc[g], 0, 0, 0);

    // gates: acc[0]=i acc[1]=f acc[2]=g acc[3]=o
    char* wb = lds0 + (cur ^ 1) * 4096;
#pragma unroll
    for (int jr = 0; jr < 4; jr++) {
      const float iv = acc[0][jr];
      const float fv = acc[1][jr];
      const float gv = acc[2][jr];
      const float ov = acc[3][jr];
      const float cn = sigf(fv) * c[jr] + sigf(iv) * tanh_fast(gv);
      c[jr] = cn;
      const float hn = sigf(ov) * tanh_fast(cn);
      *(f16*)(wb + wro[jr]) = (f16)hn;
    }
    __syncthreads();
#pragma unroll
    for (int kc = 0; kc < 4; kc++) axc[kc] = axn[kc];
    cur ^= 1;
  }

  // ---- head: out = tanh(h @ W1^T + b1) @ W2^T + b2 ----
  {
    char* rb = lds0 + cur * 4096;
    f16x8 ah[4];
#pragma unroll
    for (int kc = 0; kc < 4; kc++) ah[kc] = *(const f16x8*)(rb + rdo[kc]);
    const float* W1 = hW1 + (size_t)k * NH * NH;
    const int col = w * 16 + lr;
    f32x4 hacc;
    {
      const float b1 = hb1[k * NH + col];
      f32x4 binit = {b1, b1, b1, b1};
      hacc = binit;
    }
#pragma unroll
    for (int kc = 0; kc < 4; kc++) {
      const float* wrow = W1 + (size_t)col * NH + kc * 32 + kg * 8;
      const f32x4 w0 = *(const f32x4*)(wrow);
      const f32x4 w1 = *(const f32x4*)(wrow + 4);
      f16x8 wv;
      wv[0] = (f16)w0[0]; wv[1] = (f16)w0[1]; wv[2] = (f16)w0[2]; wv[3] = (f16)w0[3];
      wv[4] = (f16)w1[0]; wv[5] = (f16)w1[1]; wv[6] = (f16)w1[2]; wv[7] = (f16)w1[3];
      hacc = __builtin_amdgcn_mfma_f32_16x16x32_f16(ah[kc], wv, hacc, 0, 0, 0);
    }
#pragma unroll
    for (int jr = 0; jr < 4; jr++)
      hu[(kg * 4 + jr) * NH + col] = tanh_fast(hacc[jr]);
  }
  __syncthreads();
  if (w == 0) {
    const int b = l >> 2, part = l & 3;
    const float* W2 = hW2 + (size_t)k * NH;
    float s = 0.f;
#pragma unroll
    for (int j = 0; j < 32; j++)
      s += hu[b * NH + part * 32 + j] * W2[part * 32 + j];
    s += __shfl_xor(s, 1);
    s += __shfl_xor(s, 2);
    if (part == 0) out[k * NB + b0 + b] = s + hb2[k];
  }
}

// ------------------------------------------------------------- launch -------
extern "C" void kernel_launch(void* const* d_in, const int* in_sizes, int n_in,
                              void* d_out, int out_size, void* d_ws, size_t ws_size,
                              hipStream_t stream) {
  (void)in_sizes; (void)n_in; (void)out_size; (void)ws_size;
  const float* x = (const float*)d_in[0];
  const float* t0 = (const float*)d_in[1];
  const float* node = (const float*)d_in[2];
  const float* tau = (const float*)d_in[3];
  const float* endi = (const float*)d_in[4];
  const float* coords = (const float*)d_in[5];
  const float* Wx1 = (const float*)d_in[6];
  const float* Wx2 = (const float*)d_in[7];
  const float* bx2 = (const float*)d_in[8];
  const float* Wres = (const float*)d_in[9];
  const float* bres = (const float*)d_in[10];
  const float* Wnode = (const float*)d_in[11];
  const float* Wtau = (const float*)d_in[12];
  const float* btau = (const float*)d_in[13];
  const float* Wend1 = (const float*)d_in[14];
  const float* Wend2 = (const float*)d_in[15];
  const float* bend2 = (const float*)d_in[16];
  const float* Wcoord = (const float*)d_in[17];
  const float* Wih = (const float*)d_in[18];
  const float* Whh = (const float*)d_in[19];
  const float* bih = (const float*)d_in[20];
  const float* bhh = (const float*)d_in[21];
  const float* hW1 = (const float*)d_in[22];
  const float* hb1 = (const float*)d_in[23];
  const float* hW2 = (const float*)d_in[24];
  const float* hb2 = (const float*)d_in[25];

  char* ws = (char*)d_ws;
  f16* xh = (f16*)ws;      ws += (size_t)NB * NH * 2;
  f16* t0h = (f16*)ws;     ws += (size_t)NB * NH * 2;
  f16* endh = (f16*)ws;    ws += (size_t)NB * NH * 2;
  f16* tauh = (f16*)ws;    ws += (size_t)NB * NL * NH * 2;
  f16* nodeh = (f16*)ws;   ws += (size_t)NB * 2 * NL * NH * 2;
  f16* coordh = (f16*)ws;  ws += (size_t)NB * 2 * NL * NH * 2;
  f16* Wf = (f16*)ws;      ws += (size_t)NSTEP * 4096 * 2;
  f16* Wih16 = (f16*)ws;   ws += (size_t)7 * 512 * NH * 2;
  f16* Whh16 = (f16*)ws;   ws += (size_t)7 * 512 * NH * 2;
  float* bsum = (float*)ws;

  prep_kernel<<<1024, 256, 0, stream>>>(
      x, t0, tau, endi, coords, Wx1, Wx2, bx2, Wres, bres, Wnode, Wtau, btau,
      Wend1, Wend2, bend2, Wcoord, Wih, Whh, bih, bhh,
      xh, t0h, endh, tauh, coordh, Wf, Wih16, Whh16, bsum);
  node_gemm<<<256, 512, 0, stream>>>(node, Wf, nodeh);
  lstm_run<<<224, 512, 0, stream>>>(xh, t0h, endh, tauh, nodeh, coordh,
                                    Wih16, Whh16, bsum, hW1, hb1, hW2, hb2,
                                    (float*)d_out);
}

// Round 8
// 323.930 us; speedup vs baseline: 1.3439x; 1.3439x over previous
//
#include <hip/hip_runtime.h>
#include <hip/hip_fp16.h>

typedef _Float16 f16;
typedef _Float16 f16x8 __attribute__((ext_vector_type(8)));
typedef float f32x4 __attribute__((ext_vector_type(4)));

#define NB 512
#define NL 16
#define NK 10000
#define NH 128
#define NSF 316    // Wf 32-k sub-steps, zero-padded (79 * 4)
#define NT128 79   // K-steps of 128

__device__ __forceinline__ float fast_exp2(float x) {
#if __has_builtin(__builtin_amdgcn_exp2f)
  return __builtin_amdgcn_exp2f(x);
#else
  return exp2f(x);
#endif
}
__device__ __forceinline__ float fast_rcp(float x) {
#if __has_builtin(__builtin_amdgcn_rcpf)
  return __builtin_amdgcn_rcpf(x);
#else
  return 1.f / x;
#endif
}
__device__ __forceinline__ float sigf(float x) {
  return fast_rcp(1.f + fast_exp2(-1.44269504f * x));
}
__device__ __forceinline__ float tanh_fast(float x) {
  return 2.f * fast_rcp(1.f + fast_exp2(-2.88539008f * x)) - 1.f;
}

__device__ __forceinline__ void gload16(const void* g, void* l) {
  __builtin_amdgcn_global_load_lds(
      (const __attribute__((address_space(1))) unsigned int*)g,
      (__attribute__((address_space(3))) unsigned int*)l, 16, 0, 0);
}

// ---------------------------------------------------------------- prep ------
// Wf: B in MFMA-fragment order: [s][nt][lane][e] with lane=(kg*16+lr),
// value = Wnode[col=nt*16+lr][k=s*32+kg*8+e], zero-padded past K=10000.
__global__ void prep_kernel(
    const float* __restrict__ x, const float* __restrict__ t0,
    const float* __restrict__ tau, const float* __restrict__ endi,
    const float* __restrict__ coords,
    const float* __restrict__ Wx1, const float* __restrict__ Wx2,
    const float* __restrict__ bx2, const float* __restrict__ Wres,
    const float* __restrict__ bres, const float* __restrict__ Wnode,
    const float* __restrict__ Wtau, const float* __restrict__ btau,
    const float* __restrict__ Wend1, const float* __restrict__ Wend2,
    const float* __restrict__ bend2, const float* __restrict__ Wcoord,
    const float* __restrict__ Wih, const float* __restrict__ Whh,
    const float* __restrict__ bih, const float* __restrict__ bhh,
    f16* __restrict__ xh, f16* __restrict__ t0h, f16* __restrict__ endh,
    f16* __restrict__ tauh, f16* __restrict__ coordh, f16* __restrict__ Wf,
    f16* __restrict__ Wih16, f16* __restrict__ Whh16, float* __restrict__ bsum) {
  const int tid0 = blockIdx.x * blockDim.x + threadIdx.x;
  const int stride = gridDim.x * blockDim.x;

  const int nWf = NSF * 4096;       // 1,294,336 (incl. zero tail)
  const int nW = 7 * 512 * NH;      // 458,752
  const int nb = 7 * 512;
  const int nxh = NB * NH;          // 65,536
  const int ntau = NB * NL * NH;    // 1,048,576
  const int nco = NB * 2 * NL * NH; // 2,097,152

  for (int i = tid0; i < nWf; i += stride) {
    const int s = i >> 12, r = i & 4095;
    const int nt = r >> 9, l2 = r & 511;
    const int lane = l2 >> 3, e = l2 & 7;
    const int kg = lane >> 4, lr = lane & 15;
    const int col = nt * 16 + lr;
    const int k = s * 32 + kg * 8 + e;
    Wf[i] = (k < NK) ? (f16)Wnode[(size_t)col * NK + k] : (f16)0.f;
  }
  for (int i = tid0; i < nW; i += stride) {
    Wih16[i] = (f16)Wih[i];
    Whh16[i] = (f16)Whh[i];
  }
  for (int i = tid0; i < nb; i += stride) bsum[i] = bih[i] + bhh[i];
  for (int i = tid0; i < nxh; i += stride) {
    const int b = i >> 7, h = i & 127;
    const float s = x[2 * b] * Wx1[0] + x[2 * b + 1] * Wx1[1];
    xh[i] = (f16)tanhf(s * Wx2[h] + bx2[h]);
    t0h[i] = (f16)tanhf(t0[b] * Wres[h] + bres[h]);
    const float e = endi[2 * b] * Wend1[0] + endi[2 * b + 1] * Wend1[1];
    endh[i] = (f16)(e * Wend2[h] + bend2[h]);
  }
  for (int i = tid0; i < ntau; i += stride) {
    const int h = i & 127, bl = i >> 7;
    tauh[i] = (f16)tanhf(tau[bl] * Wtau[h] + btau[h]);
  }
  for (int i = tid0; i < nco; i += stride) {
    const int h = i & 127, br = i >> 7;
    coordh[i] = (f16)(coords[2 * br] * Wcoord[2 * h] +
                      coords[2 * br + 1] * Wcoord[2 * h + 1]);
  }
}

// ------------------------------------------------------------ node GEMM -----
// C(16384x128,f16) = A(16384x10000,f32) * W^T. Grid 256 wgs (1/CU), 512 thr.
// Tile = 64 rows x 128 k f32 (32 KB A), 3-deep LDS ring (96 KB). A staged via
// global_load_lds (pre-swizzled source, XOR row swizzle); counted
// s_waitcnt vmcnt(8) + raw s_barrier (queue never drains). B fragments
// (L2-resident Wf) double-buffered in VGPRs via ping-pong unroll-2.
// Wave w: rows [(w&3)*16,+16), cols [(w>>2)*64,+64); 16 MFMA/iter.
__global__ __launch_bounds__(512, 2) void node_gemm(const float* __restrict__ A,
                                                    const f16* __restrict__ Wf,
                                                    f16* __restrict__ Cn) {
  __shared__ char lds[3][32768];
  const int tid = threadIdx.x;
  const int w = tid >> 6, l = tid & 63;
  const int lr = l & 15, kg = l >> 4;
  const int r0 = blockIdx.x * 64;
  char* lds0 = &lds[0][0];

  // ---- staging: 4 issues/lane; issue i = rows w*8+i*2+(l>>5), 16B chunks.
  const char* ap[4];
  int bnd[4];
#pragma unroll
  for (int i = 0; i < 4; i++) {
    const int row = w * 8 + i * 2 + (l >> 5);
    const int bswz = ((l & 31) * 16) ^ ((row & 7) << 4);
    ap[i] = (const char*)A + (size_t)(r0 + row) * 40000 + bswz;
    bnd[i] = 39984 - bswz;  // joint clamp keeps 16B load in-bounds
  }

  // ---- compute assignment ----
  const int rs = w & 3;          // 16-row subtile
  const int nt0 = (w >> 2) * 4;  // col-tile base (4 tiles = 64 cols)
  int rdoA[4][2];
#pragma unroll
  for (int ks = 0; ks < 4; ks++) {
    const int row = rs * 16 + lr;
    const int s = (row & 7) << 4;
#pragma unroll
    for (int h = 0; h < 2; h++)
      rdoA[ks][h] = row * 512 + ((ks * 128 + kg * 32 + h * 16) ^ s);
  }

  f32x4 acc[4];
#pragma unroll
  for (int j = 0; j < 4; j++) {
    f32x4 z = {0.f, 0.f, 0.f, 0.f};
    acc[j] = z;
  }

  auto stage = [&](int t, int buf) {
    char* db = lds0 + buf * 32768 + w * 4096;
    const int tb = t * 512;
#pragma unroll
    for (int i = 0; i < 4; i++) {
      const int off = tb < bnd[i] ? tb : bnd[i];
      gload16(ap[i] + off, db + i * 1024);
    }
  };

  auto loadB = [&](int t, f16x8 (&B)[4][4]) {
    const f16* bp = Wf + (size_t)(4 * t) * 4096 + nt0 * 512 + l * 8;
#pragma unroll
    for (int j = 0; j < 4; j++)
#pragma unroll
      for (int ks = 0; ks < 4; ks++)
        B[j][ks] = *(const f16x8*)(bp + (size_t)ks * 4096 + j * 512);
  };

  auto compute = [&](int buf, const f16x8 (&B)[4][4]) {
    const char* cb = lds0 + buf * 32768;
#pragma unroll
    for (int ks = 0; ks < 4; ks++) {
      const f32x4 a0 = *(const f32x4*)(cb + rdoA[ks][0]);
      const f32x4 a1 = *(const f32x4*)(cb + rdoA[ks][1]);
      f16x8 af;
      af[0] = (f16)a0[0]; af[1] = (f16)a0[1]; af[2] = (f16)a0[2]; af[3] = (f16)a0[3];
      af[4] = (f16)a1[0]; af[5] = (f16)a1[1]; af[6] = (f16)a1[2]; af[7] = (f16)a1[3];
#pragma unroll
      for (int j = 0; j < 4; j++)
        acc[j] = __builtin_amdgcn_mfma_f32_16x16x32_f16(af, B[j][ks], acc[j], 0, 0, 0);
    }
  };

  f16x8 BA[4][4], BB[4][4];

  // prologue: stages first (oldest in FIFO), then B(0) regs
  stage(0, 0);
  stage(1, 1);
  loadB(0, BA);

  int cur = 0;
  auto iter = [&](int t, const f16x8 (&Bu)[4][4], f16x8 (&Bp)[4][4]) {
    asm volatile("s_waitcnt vmcnt(8)" ::: "memory");
    __builtin_amdgcn_s_barrier();
    if (t + 2 < NT128) {
      const int wb = cur >= 1 ? cur - 1 : 2;  // (cur+2)%3
      stage(t + 2, wb);
    }
    loadB(t + 1, Bp);  // prefetch next B (t+1 <= 78 always in paired iters)
    compute(cur, Bu);
    cur = cur == 2 ? 0 : cur + 1;
  };

  for (int t = 0; t < NT128 - 1; t += 2) {
    iter(t, BA, BB);
    iter(t + 1, BB, BA);
  }
  // final iteration t = 78 (uses BA, no prefetch)
  asm volatile("s_waitcnt vmcnt(0)" ::: "memory");
  __builtin_amdgcn_s_barrier();
  compute(cur, BA);

  // C write: row=(lane>>4)*4+reg, col=lane&15 within each 16x16 tile
  f16* crow = Cn + (size_t)(r0 + rs * 16 + kg * 4) * NH + nt0 * 16 + lr;
#pragma unroll
  for (int j = 0; j < 4; j++)
#pragma unroll
    for (int jr = 0; jr < 4; jr++)
      crow[(size_t)jr * NH + j * 16] = (f16)acc[j][jr];
}

// --------------------------------------------------------------- LSTM -------
// grid: 7 k's x 32 batch-chunks of 16. One wg = 8 waves (512 thr); wave w
// owns hidden units [w*16, w*16+16) across all four gates (4 gate-tiles).
// Wih/Whh fragments in VGPRs (~128), x prefetched 1 step ahead. x-MFMAs run
// before h-MFMAs so the ds_read(h) latency hides under them.
__global__ __launch_bounds__(512, 2) void lstm_run(
    const f16* __restrict__ xh, const f16* __restrict__ t0h,
    const f16* __restrict__ endh, const f16* __restrict__ tauh,
    const f16* __restrict__ nodeh, const f16* __restrict__ coordh,
    const f16* __restrict__ Wih16, const f16* __restrict__ Whh16,
    const float* __restrict__ bsum, const float* __restrict__ hW1,
    const float* __restrict__ hb1, const float* __restrict__ hW2,
    const float* __restrict__ hb2, float* __restrict__ out) {
  __shared__ f16 hbuf[2][16 * NH];  // double-buffered h, XOR-swizzled bytes
  __shared__ float hu[16 * NH];

  const int k = blockIdx.x >> 5;
  const int b0 = (blockIdx.x & 31) << 4;
  const int w = threadIdx.x >> 6;
  const int l = threadIdx.x & 63;
  const int lr = l & 15, kg = l >> 4;

  int len;
  switch (k) {
    case 0: len = 83; break;
    case 1: len = 19; break;
    case 2: len = 32; break;
    case 3: len = 32; break;
    case 4: len = 51; break;
    case 5: len = 64; break;
    default: len = 51; break;
  }

  // per-step input fragment pointer (wave-uniform select logic)
  auto xptr = [&](int t) -> const f16* {
    const f16* cb; int bstr, idx;
    if (k == 2) { cb = nodeh; bstr = 32 * NH; idx = t; }
    else if (k == 3) { cb = coordh; bstr = 32 * NH; idx = t; }
    else if (k == 5) {
      const int q = t >> 2, r = t & 3;
      cb = (r == 0 || r == 2) ? nodeh : coordh;
      bstr = 32 * NH;
      idx = 2 * q + ((r >= 2) ? 1 : 0);
    } else {
      if (t == 0) { cb = xh; bstr = NH; idx = 0; }
      else if (t == 1) { cb = t0h; bstr = NH; idx = 0; }
      else if (t == len - 1) { cb = endh; bstr = NH; idx = 0; }
      else {
        const int u = t - 2;
        if (k == 0) {
          const int q = u / 5, r = u - 5 * q;
          if (r == 0) { cb = tauh; bstr = 16 * NH; idx = q; }
          else if (r == 1) { cb = nodeh; bstr = 32 * NH; idx = 2 * q; }
          else if (r == 2) { cb = coordh; bstr = 32 * NH; idx = 2 * q; }
          else if (r == 3) { cb = nodeh; bstr = 32 * NH; idx = 2 * q + 1; }
          else { cb = coordh; bstr = 32 * NH; idx = 2 * q + 1; }
        } else if (k == 1) { cb = tauh; bstr = 16 * NH; idx = u; }
        else if (k == 4) {
          const int q = u / 3, r = u - 3 * q;
          if (r == 0) { cb = tauh; bstr = 16 * NH; idx = q; }
          else { cb = nodeh; bstr = 32 * NH; idx = 2 * q + (r - 1); }
        } else {  // k == 6
          const int q = u / 3, r = u - 3 * q;
          if (r == 0) { cb = tauh; bstr = 16 * NH; idx = q; }
          else { cb = coordh; bstr = 32 * NH; idx = 2 * q + (r - 1); }
        }
      }
    }
    return cb + (size_t)(b0 + lr) * bstr + idx * NH + kg * 8;
  };

  // ---- load weight fragments into registers ----
  // wave w owns hidden cols [w*16, w*16+16); gate g's row block = g*128.
  f16x8 Wh[4][4], Wi[4][4];
  float bias[4];
  {
    const f16* whb = Whh16 + (size_t)k * 512 * NH;
    const f16* wib = Wih16 + (size_t)k * 512 * NH;
#pragma unroll
    for (int g = 0; g < 4; g++) {
      const int col = g * 128 + w * 16 + lr;
      bias[g] = bsum[k * 512 + col];
#pragma unroll
      for (int kc = 0; kc < 4; kc++) {
        Wh[kc][g] = *(const f16x8*)(whb + (size_t)col * NH + kc * 32 + kg * 8);
        Wi[kc][g] = *(const f16x8*)(wib + (size_t)col * NH + kc * 32 + kg * 8);
      }
    }
  }

  char* lds0 = (char*)&hbuf[0][0];
  // zero h buffer 0 (h0 = 0): 512 threads x 8 B = 4096 B
  *(unsigned long long*)(lds0 + threadIdx.x * 8) = 0ull;
  __syncthreads();

  float c[4] = {0, 0, 0, 0};

  // precomputed swizzled LDS byte offsets (constant across t)
  int rdo[4];
#pragma unroll
  for (int kc = 0; kc < 4; kc++) {
    const int colb = (kc * 32 + kg * 8) * 2;
    rdo[kc] = lr * 256 + (colb ^ ((lr & 7) << 4));
  }
  int wro[4];
#pragma unroll
  for (int jr = 0; jr < 4; jr++) {
    const int hrow = kg * 4 + jr;
    const int hcol = w * 16 + lr;
    wro[jr] = hrow * 256 + ((hcol * 2) ^ ((hrow & 7) << 4));
  }

  // prime x for t=0
  f16x8 axc[4];
  {
    const f16* xp = xptr(0);
#pragma unroll
    for (int kc = 0; kc < 4; kc++) axc[kc] = *(const f16x8*)(xp + kc * 32);
  }

  int cur = 0;
  for (int t = 0; t < len; t++) {
    char* rb = lds0 + cur * 4096;
    f16x8 ah[4];
#pragma unroll
    for (int kc = 0; kc < 4; kc++) ah[kc] = *(const f16x8*)(rb + rdo[kc]);

    // prefetch next-step x into registers (hidden under MFMA+gates+barrier)
    f16x8 axn[4];
    if (t + 1 < len) {
      const f16* xp = xptr(t + 1);
#pragma unroll
      for (int kc = 0; kc < 4; kc++) axn[kc] = *(const f16x8*)(xp + kc * 32);
    }

    f32x4 acc[4];
#pragma unroll
    for (int g = 0; g < 4; g++) {
      f32x4 binit = {bias[g], bias[g], bias[g], bias[g]};
      acc[g] = binit;
    }
    // x-part first (register operands ready) -> hides ds_read(h) latency
#pragma unroll
    for (int kc = 0; kc < 4; kc++)
#pragma unroll
      for (int g = 0; g < 4; g++)
        acc[g] = __builtin_amdgcn_mfma_f32_16x16x32_f16(axc[kc], Wi[kc][g], acc[g], 0, 0, 0);
#pragma unroll
    for (int kc = 0; kc < 4; kc++)
#pragma unroll
      for (int g = 0; g < 4; g++)
        acc[g] = __builtin_amdgcn_mfma_f32_16x16x32_f16(ah[kc], Wh[kc][g], acc[g], 0, 0, 0);

    // gates: acc[0]=i acc[1]=f acc[2]=g acc[3]=o
    char* wb = lds0 + (cur ^ 1) * 4096;
#pragma unroll
    for (int jr = 0; jr < 4; jr++) {
      const float iv = acc[0][jr];
      const float fv = acc[1][jr];
      const float gv = acc[2][jr];
      const float ov = acc[3][jr];
      const float cn = sigf(fv) * c[jr] + sigf(iv) * tanh_fast(gv);
      c[jr] = cn;
      const float hn = sigf(ov) * tanh_fast(cn);
      *(f16*)(wb + wro[jr]) = (f16)hn;
    }
    __syncthreads();
#pragma unroll
    for (int kc = 0; kc < 4; kc++) axc[kc] = axn[kc];
    cur ^= 1;
  }

  // ---- head: out = tanh(h @ W1^T + b1) @ W2^T + b2 ----
  {
    char* rb = lds0 + cur * 4096;
    f16x8 ah[4];
#pragma unroll
    for (int kc = 0; kc < 4; kc++) ah[kc] = *(const f16x8*)(rb + rdo[kc]);
    const float* W1 = hW1 + (size_t)k * NH * NH;
    const int col = w * 16 + lr;
    f32x4 hacc;
    {
      const float b1 = hb1[k * NH + col];
      f32x4 binit = {b1, b1, b1, b1};
      hacc = binit;
    }
#pragma unroll
    for (int kc = 0; kc < 4; kc++) {
      const float* wrow = W1 + (size_t)col * NH + kc * 32 + kg * 8;
      const f32x4 w0 = *(const f32x4*)(wrow);
      const f32x4 w1 = *(const f32x4*)(wrow + 4);
      f16x8 wv;
      wv[0] = (f16)w0[0]; wv[1] = (f16)w0[1]; wv[2] = (f16)w0[2]; wv[3] = (f16)w0[3];
      wv[4] = (f16)w1[0]; wv[5] = (f16)w1[1]; wv[6] = (f16)w1[2]; wv[7] = (f16)w1[3];
      hacc = __builtin_amdgcn_mfma_f32_16x16x32_f16(ah[kc], wv, hacc, 0, 0, 0);
    }
#pragma unroll
    for (int jr = 0; jr < 4; jr++)
      hu[(kg * 4 + jr) * NH + col] = tanh_fast(hacc[jr]);
  }
  __syncthreads();
  if (w == 0) {
    const int b = l >> 2, part = l & 3;
    const float* W2 = hW2 + (size_t)k * NH;
    float s = 0.f;
#pragma unroll
    for (int j = 0; j < 32; j++)
      s += hu[b * NH + part * 32 + j] * W2[part * 32 + j];
    s += __shfl_xor(s, 1);
    s += __shfl_xor(s, 2);
    if (part == 0) out[k * NB + b0 + b] = s + hb2[k];
  }
}

// ------------------------------------------------------------- launch -------
extern "C" void kernel_launch(void* const* d_in, const int* in_sizes, int n_in,
                              void* d_out, int out_size, void* d_ws, size_t ws_size,
                              hipStream_t stream) {
  (void)in_sizes; (void)n_in; (void)out_size; (void)ws_size;
  const float* x = (const float*)d_in[0];
  const float* t0 = (const float*)d_in[1];
  const float* node = (const float*)d_in[2];
  const float* tau = (const float*)d_in[3];
  const float* endi = (const float*)d_in[4];
  const float* coords = (const float*)d_in[5];
  const float* Wx1 = (const float*)d_in[6];
  const float* Wx2 = (const float*)d_in[7];
  const float* bx2 = (const float*)d_in[8];
  const float* Wres = (const float*)d_in[9];
  const float* bres = (const float*)d_in[10];
  const float* Wnode = (const float*)d_in[11];
  const float* Wtau = (const float*)d_in[12];
  const float* btau = (const float*)d_in[13];
  const float* Wend1 = (const float*)d_in[14];
  const float* Wend2 = (const float*)d_in[15];
  const float* bend2 = (const float*)d_in[16];
  const float* Wcoord = (const float*)d_in[17];
  const float* Wih = (const float*)d_in[18];
  const float* Whh = (const float*)d_in[19];
  const float* bih = (const float*)d_in[20];
  const float* bhh = (const float*)d_in[21];
  const float* hW1 = (const float*)d_in[22];
  const float* hb1 = (const float*)d_in[23];
  const float* hW2 = (const float*)d_in[24];
  const float* hb2 = (const float*)d_in[25];

  char* ws = (char*)d_ws;
  f16* xh = (f16*)ws;      ws += (size_t)NB * NH * 2;
  f16* t0h = (f16*)ws;     ws += (size_t)NB * NH * 2;
  f16* endh = (f16*)ws;    ws += (size_t)NB * NH * 2;
  f16* tauh = (f16*)ws;    ws += (size_t)NB * NL * NH * 2;
  f16* nodeh = (f16*)ws;   ws += (size_t)NB * 2 * NL * NH * 2;
  f16* coordh = (f16*)ws;  ws += (size_t)NB * 2 * NL * NH * 2;
  f16* Wf = (f16*)ws;      ws += (size_t)NSF * 4096 * 2;
  f16* Wih16 = (f16*)ws;   ws += (size_t)7 * 512 * NH * 2;
  f16* Whh16 = (f16*)ws;   ws += (size_t)7 * 512 * NH * 2;
  float* bsum = (float*)ws;

  prep_kernel<<<1024, 256, 0, stream>>>(
      x, t0, tau, endi, coords, Wx1, Wx2, bx2, Wres, bres, Wnode, Wtau, btau,
      Wend1, Wend2, bend2, Wcoord, Wih, Whh, bih, bhh,
      xh, t0h, endh, tauh, coordh, Wf, Wih16, Whh16, bsum);
  node_gemm<<<256, 512, 0, stream>>>(node, Wf, nodeh);
  lstm_run<<<224, 512, 0, stream>>>(xh, t0h, endh, tauh, nodeh, coordh,
                                    Wih16, Whh16, bsum, hW1, hb1, hW2, hb2,
                                    (float*)d_out);
}

// Round 9
// 299.265 us; speedup vs baseline: 1.4547x; 1.0824x over previous
//
#include <hip/hip_runtime.h>
#include <hip/hip_fp16.h>

typedef _Float16 f16;
typedef _Float16 f16x8 __attribute__((ext_vector_type(8)));
typedef float f32x4 __attribute__((ext_vector_type(4)));

#define NB 512
#define NL 16
#define NK 10000
#define NH 128
#define NSF 316    // Wf 32-k sub-steps, zero-padded (79 * 4)
#define NT128 79   // K-steps of 128

__device__ __forceinline__ float fast_exp2(float x) {
#if __has_builtin(__builtin_amdgcn_exp2f)
  return __builtin_amdgcn_exp2f(x);
#else
  return exp2f(x);
#endif
}
__device__ __forceinline__ float fast_rcp(float x) {
#if __has_builtin(__builtin_amdgcn_rcpf)
  return __builtin_amdgcn_rcpf(x);
#else
  return 1.f / x;
#endif
}
__device__ __forceinline__ float sigf(float x) {
  return fast_rcp(1.f + fast_exp2(-1.44269504f * x));
}
__device__ __forceinline__ float tanh_fast(float x) {
  return 2.f * fast_rcp(1.f + fast_exp2(-2.88539008f * x)) - 1.f;
}

__device__ __forceinline__ void gload16(const void* g, void* l) {
  __builtin_amdgcn_global_load_lds(
      (const __attribute__((address_space(1))) unsigned int*)g,
      (__attribute__((address_space(3))) unsigned int*)l, 16, 0, 0);
}

// ---------------------------------------------------------------- prep ------
// Wf: B in MFMA-fragment order: [s][nt][lane][e] with lane=(kg*16+lr),
// value = Wnode[col=nt*16+lr][k=s*32+kg*8+e], zero-padded past K=10000.
__global__ void prep_kernel(
    const float* __restrict__ x, const float* __restrict__ t0,
    const float* __restrict__ tau, const float* __restrict__ endi,
    const float* __restrict__ coords,
    const float* __restrict__ Wx1, const float* __restrict__ Wx2,
    const float* __restrict__ bx2, const float* __restrict__ Wres,
    const float* __restrict__ bres, const float* __restrict__ Wnode,
    const float* __restrict__ Wtau, const float* __restrict__ btau,
    const float* __restrict__ Wend1, const float* __restrict__ Wend2,
    const float* __restrict__ bend2, const float* __restrict__ Wcoord,
    const float* __restrict__ Wih, const float* __restrict__ Whh,
    const float* __restrict__ bih, const float* __restrict__ bhh,
    f16* __restrict__ xh, f16* __restrict__ t0h, f16* __restrict__ endh,
    f16* __restrict__ tauh, f16* __restrict__ coordh, f16* __restrict__ Wf,
    f16* __restrict__ Wih16, f16* __restrict__ Whh16, float* __restrict__ bsum) {
  const int tid0 = blockIdx.x * blockDim.x + threadIdx.x;
  const int stride = gridDim.x * blockDim.x;

  const int nWf = NSF * 4096;       // 1,294,336 (incl. zero tail)
  const int nW = 7 * 512 * NH;      // 458,752
  const int nb = 7 * 512;
  const int nxh = NB * NH;          // 65,536
  const int ntau = NB * NL * NH;    // 1,048,576
  const int nco = NB * 2 * NL * NH; // 2,097,152

  for (int i = tid0; i < nWf; i += stride) {
    const int s = i >> 12, r = i & 4095;
    const int nt = r >> 9, l2 = r & 511;
    const int lane = l2 >> 3, e = l2 & 7;
    const int kg = lane >> 4, lr = lane & 15;
    const int col = nt * 16 + lr;
    const int k = s * 32 + kg * 8 + e;
    Wf[i] = (k < NK) ? (f16)Wnode[(size_t)col * NK + k] : (f16)0.f;
  }
  for (int i = tid0; i < nW; i += stride) {
    Wih16[i] = (f16)Wih[i];
    Whh16[i] = (f16)Whh[i];
  }
  for (int i = tid0; i < nb; i += stride) bsum[i] = bih[i] + bhh[i];
  for (int i = tid0; i < nxh; i += stride) {
    const int b = i >> 7, h = i & 127;
    const float s = x[2 * b] * Wx1[0] + x[2 * b + 1] * Wx1[1];
    xh[i] = (f16)tanhf(s * Wx2[h] + bx2[h]);
    t0h[i] = (f16)tanhf(t0[b] * Wres[h] + bres[h]);
    const float e = endi[2 * b] * Wend1[0] + endi[2 * b + 1] * Wend1[1];
    endh[i] = (f16)(e * Wend2[h] + bend2[h]);
  }
  for (int i = tid0; i < ntau; i += stride) {
    const int h = i & 127, bl = i >> 7;
    tauh[i] = (f16)tanhf(tau[bl] * Wtau[h] + btau[h]);
  }
  for (int i = tid0; i < nco; i += stride) {
    const int h = i & 127, br = i >> 7;
    coordh[i] = (f16)(coords[2 * br] * Wcoord[2 * h] +
                      coords[2 * br + 1] * Wcoord[2 * h + 1]);
  }
}

// ------------------------------------------------------------ node GEMM -----
// C(16384x128,f16) = A(16384x10000,f32) * W^T. Grid 256 wgs (1/CU), 512 thr.
// Tile = 64 rows x 128 k f32 (32 KB A), 4-deep LDS ring (128 KB). At each
// EVEN iteration, stages for tiles e+2 AND e+3 are issued back-to-back per
// row-slot -> each row gets a 1-KB contiguous HBM burst (DRAM page locality).
// One counted s_waitcnt vmcnt(16) + one s_barrier per 2 tiles; odd iters run
// free. B fragments (L2-resident Wf) ping-pong in VGPRs, issued in FIFO order
// [loadB(e+1)][burst(e+2)][loadB(e+2)] so implicit B-waits never retire the
// A-burst early. Wave w: rows [(w&3)*16,+16), cols [(w>>2)*64,+64).
__global__ __launch_bounds__(512, 2) void node_gemm(const float* __restrict__ A,
                                                    const f16* __restrict__ Wf,
                                                    f16* __restrict__ Cn) {
  __shared__ char lds[4][32768];
  const int tid = threadIdx.x;
  const int w = tid >> 6, l = tid & 63;
  const int lr = l & 15, kg = l >> 4;
  const int r0 = blockIdx.x * 64;
  char* lds0 = &lds[0][0];

  // ---- staging slots: slot i covers rows w*8+i*2+(l>>5), 16B per lane ----
  const char* ap[4];
  int bnd[4];
#pragma unroll
  for (int i = 0; i < 4; i++) {
    const int row = w * 8 + i * 2 + (l >> 5);
    const int bswz = ((l & 31) * 16) ^ ((row & 7) << 4);
    ap[i] = (const char*)A + (size_t)(r0 + row) * 40000 + bswz;
    bnd[i] = 39984 - bswz;  // clamp keeps 16B load in-bounds; Wf pad zeros it
  }

  // ---- compute assignment ----
  const int rs = w & 3;          // 16-row subtile
  const int nt0 = (w >> 2) * 4;  // col-tile base (4 tiles = 64 cols)
  int rdoA[4][2];
#pragma unroll
  for (int ks = 0; ks < 4; ks++) {
    const int row = rs * 16 + lr;
    const int s = (row & 7) << 4;
#pragma unroll
    for (int h = 0; h < 2; h++)
      rdoA[ks][h] = row * 512 + ((ks * 128 + kg * 32 + h * 16) ^ s);
  }

  f32x4 acc[4];
#pragma unroll
  for (int j = 0; j < 4; j++) {
    f32x4 z = {0.f, 0.f, 0.f, 0.f};
    acc[j] = z;
  }

  // stage tiles ta and ta+1 (ta even): per slot, the two 512-B chunks of the
  // same row-pair are issued consecutively -> 1 KB contiguous per row.
  auto burst = [&](int ta) {
    const int tb0 = ta * 512, tb1 = tb0 + 512;
    char* d0 = lds0 + (ta & 3) * 32768 + w * 4096;
    char* d1 = lds0 + ((ta + 1) & 3) * 32768 + w * 4096;
    const bool two = (ta + 1 < NT128);
#pragma unroll
    for (int i = 0; i < 4; i++) {
      gload16(ap[i] + (tb0 < bnd[i] ? tb0 : bnd[i]), d0 + i * 1024);
      if (two) gload16(ap[i] + (tb1 < bnd[i] ? tb1 : bnd[i]), d1 + i * 1024);
    }
  };

  auto loadB = [&](int t, f16x8 (&B)[4][4]) {
    const f16* bp = Wf + (size_t)(4 * t) * 4096 + nt0 * 512 + l * 8;
#pragma unroll
    for (int j = 0; j < 4; j++)
#pragma unroll
      for (int ks = 0; ks < 4; ks++)
        B[j][ks] = *(const f16x8*)(bp + (size_t)ks * 4096 + j * 512);
  };

  auto compute = [&](int buf, const f16x8 (&B)[4][4]) {
    const char* cb = lds0 + buf * 32768;
#pragma unroll
    for (int ks = 0; ks < 4; ks++) {
      const f32x4 a0 = *(const f32x4*)(cb + rdoA[ks][0]);
      const f32x4 a1 = *(const f32x4*)(cb + rdoA[ks][1]);
      f16x8 af;
      af[0] = (f16)a0[0]; af[1] = (f16)a0[1]; af[2] = (f16)a0[2]; af[3] = (f16)a0[3];
      af[4] = (f16)a1[0]; af[5] = (f16)a1[1]; af[6] = (f16)a1[2]; af[7] = (f16)a1[3];
#pragma unroll
      for (int j = 0; j < 4; j++)
        acc[j] = __builtin_amdgcn_mfma_f32_16x16x32_f16(af, B[j][ks], acc[j], 0, 0, 0);
    }
  };

  f16x8 BA[4][4], BB[4][4];

  // prologue: burst for tiles 0,1 (8 instrs, oldest in FIFO), then B(0)
  burst(0);
  loadB(0, BA);

  for (int e = 0; e < NT128; e += 2) {
    // retire the burst issued 2 iters ago (8 instrs); keep loadB(e) in flight
    asm volatile("s_waitcnt vmcnt(16)" ::: "memory");
    __builtin_amdgcn_s_barrier();
    if (e + 1 < NT128) loadB(e + 1, BB);
    if (e + 2 < NT128) burst(e + 2);
    compute(e & 3, BA);
    if (e + 1 < NT128) {
      if (e + 2 < NT128) loadB(e + 2, BA);
      compute((e + 1) & 3, BB);
    }
  }

  // C write: row=(lane>>4)*4+reg, col=lane&15 within each 16x16 tile
  f16* crow = Cn + (size_t)(r0 + rs * 16 + kg * 4) * NH + nt0 * 16 + lr;
#pragma unroll
  for (int j = 0; j < 4; j++)
#pragma unroll
    for (int jr = 0; jr < 4; jr++)
      crow[(size_t)jr * NH + j * 16] = (f16)acc[j][jr];
}

// --------------------------------------------------------------- LSTM -------
// grid: 7 k's x 32 batch-chunks of 16. One wg = 8 waves (512 thr); wave w
// owns hidden units [w*16, w*16+16) across all four gates (4 gate-tiles).
// Wih/Whh fragments in VGPRs (~128), x prefetched 1 step ahead. x-MFMAs run
// before h-MFMAs so the ds_read(h) latency hides under them.
__global__ __launch_bounds__(512, 2) void lstm_run(
    const f16* __restrict__ xh, const f16* __restrict__ t0h,
    const f16* __restrict__ endh, const f16* __restrict__ tauh,
    const f16* __restrict__ nodeh, const f16* __restrict__ coordh,
    const f16* __restrict__ Wih16, const f16* __restrict__ Whh16,
    const float* __restrict__ bsum, const float* __restrict__ hW1,
    const float* __restrict__ hb1, const float* __restrict__ hW2,
    const float* __restrict__ hb2, float* __restrict__ out) {
  __shared__ f16 hbuf[2][16 * NH];  // double-buffered h, XOR-swizzled bytes
  __shared__ float hu[16 * NH];

  const int k = blockIdx.x >> 5;
  const int b0 = (blockIdx.x & 31) << 4;
  const int w = threadIdx.x >> 6;
  const int l = threadIdx.x & 63;
  const int lr = l & 15, kg = l >> 4;

  int len;
  switch (k) {
    case 0: len = 83; break;
    case 1: len = 19; break;
    case 2: len = 32; break;
    case 3: len = 32; break;
    case 4: len = 51; break;
    case 5: len = 64; break;
    default: len = 51; break;
  }

  // per-step input fragment pointer (wave-uniform select logic)
  auto xptr = [&](int t) -> const f16* {
    const f16* cb; int bstr, idx;
    if (k == 2) { cb = nodeh; bstr = 32 * NH; idx = t; }
    else if (k == 3) { cb = coordh; bstr = 32 * NH; idx = t; }
    else if (k == 5) {
      const int q = t >> 2, r = t & 3;
      cb = (r == 0 || r == 2) ? nodeh : coordh;
      bstr = 32 * NH;
      idx = 2 * q + ((r >= 2) ? 1 : 0);
    } else {
      if (t == 0) { cb = xh; bstr = NH; idx = 0; }
      else if (t == 1) { cb = t0h; bstr = NH; idx = 0; }
      else if (t == len - 1) { cb = endh; bstr = NH; idx = 0; }
      else {
        const int u = t - 2;
        if (k == 0) {
          const int q = u / 5, r = u - 5 * q;
          if (r == 0) { cb = tauh; bstr = 16 * NH; idx = q; }
          else if (r == 1) { cb = nodeh; bstr = 32 * NH; idx = 2 * q; }
          else if (r == 2) { cb = coordh; bstr = 32 * NH; idx = 2 * q; }
          else if (r == 3) { cb = nodeh; bstr = 32 * NH; idx = 2 * q + 1; }
          else { cb = coordh; bstr = 32 * NH; idx = 2 * q + 1; }
        } else if (k == 1) { cb = tauh; bstr = 16 * NH; idx = u; }
        else if (k == 4) {
          const int q = u / 3, r = u - 3 * q;
          if (r == 0) { cb = tauh; bstr = 16 * NH; idx = q; }
          else { cb = nodeh; bstr = 32 * NH; idx = 2 * q + (r - 1); }
        } else {  // k == 6
          const int q = u / 3, r = u - 3 * q;
          if (r == 0) { cb = tauh; bstr = 16 * NH; idx = q; }
          else { cb = coordh; bstr = 32 * NH; idx = 2 * q + (r - 1); }
        }
      }
    }
    return cb + (size_t)(b0 + lr) * bstr + idx * NH + kg * 8;
  };

  // ---- load weight fragments into registers ----
  // wave w owns hidden cols [w*16, w*16+16); gate g's row block = g*128.
  f16x8 Wh[4][4], Wi[4][4];
  float bias[4];
  {
    const f16* whb = Whh16 + (size_t)k * 512 * NH;
    const f16* wib = Wih16 + (size_t)k * 512 * NH;
#pragma unroll
    for (int g = 0; g < 4; g++) {
      const int col = g * 128 + w * 16 + lr;
      bias[g] = bsum[k * 512 + col];
#pragma unroll
      for (int kc = 0; kc < 4; kc++) {
        Wh[kc][g] = *(const f16x8*)(whb + (size_t)col * NH + kc * 32 + kg * 8);
        Wi[kc][g] = *(const f16x8*)(wib + (size_t)col * NH + kc * 32 + kg * 8);
      }
    }
  }

  char* lds0 = (char*)&hbuf[0][0];
  // zero h buffer 0 (h0 = 0): 512 threads x 8 B = 4096 B
  *(unsigned long long*)(lds0 + threadIdx.x * 8) = 0ull;
  __syncthreads();

  float c[4] = {0, 0, 0, 0};

  // precomputed swizzled LDS byte offsets (constant across t)
  int rdo[4];
#pragma unroll
  for (int kc = 0; kc < 4; kc++) {
    const int colb = (kc * 32 + kg * 8) * 2;
    rdo[kc] = lr * 256 + (colb ^ ((lr & 7) << 4));
  }
  int wro[4];
#pragma unroll
  for (int jr = 0; jr < 4; jr++) {
    const int hrow = kg * 4 + jr;
    const int hcol = w * 16 + lr;
    wro[jr] = hrow * 256 + ((hcol * 2) ^ ((hrow & 7) << 4));
  }

  // prime x for t=0
  f16x8 axc[4];
  {
    const f16* xp = xptr(0);
#pragma unroll
    for (int kc = 0; kc < 4; kc++) axc[kc] = *(const f16x8*)(xp + kc * 32);
  }

  int cur = 0;
  for (int t = 0; t < len; t++) {
    char* rb = lds0 + cur * 4096;
    f16x8 ah[4];
#pragma unroll
    for (int kc = 0; kc < 4; kc++) ah[kc] = *(const f16x8*)(rb + rdo[kc]);

    // prefetch next-step x into registers (hidden under MFMA+gates+barrier)
    f16x8 axn[4];
    if (t + 1 < len) {
      const f16* xp = xptr(t + 1);
#pragma unroll
      for (int kc = 0; kc < 4; kc++) axn[kc] = *(const f16x8*)(xp + kc * 32);
    }

    f32x4 acc[4];
#pragma unroll
    for (int g = 0; g < 4; g++) {
      f32x4 binit = {bias[g], bias[g], bias[g], bias[g]};
      acc[g] = binit;
    }
    // x-part first (register operands ready) -> hides ds_read(h) latency
#pragma unroll
    for (int kc = 0; kc < 4; kc++)
#pragma unroll
      for (int g = 0; g < 4; g++)
        acc[g] = __builtin_amdgcn_mfma_f32_16x16x32_f16(axc[kc], Wi[kc][g], acc[g], 0, 0, 0);
#pragma unroll
    for (int kc = 0; kc < 4; kc++)
#pragma unroll
      for (int g = 0; g < 4; g++)
        acc[g] = __builtin_amdgcn_mfma_f32_16x16x32_f16(ah[kc], Wh[kc][g], acc[g], 0, 0, 0);

    // gates: acc[0]=i acc[1]=f acc[2]=g acc[3]=o
    char* wb = lds0 + (cur ^ 1) * 4096;
#pragma unroll
    for (int jr = 0; jr < 4; jr++) {
      const float iv = acc[0][jr];
      const float fv = acc[1][jr];
      const float gv = acc[2][jr];
      const float ov = acc[3][jr];
      const float cn = sigf(fv) * c[jr] + sigf(iv) * tanh_fast(gv);
      c[jr] = cn;
      const float hn = sigf(ov) * tanh_fast(cn);
      *(f16*)(wb + wro[jr]) = (f16)hn;
    }
    __syncthreads();
#pragma unroll
    for (int kc = 0; kc < 4; kc++) axc[kc] = axn[kc];
    cur ^= 1;
  }

  // ---- head: out = tanh(h @ W1^T + b1) @ W2^T + b2 ----
  {
    char* rb = lds0 + cur * 4096;
    f16x8 ah[4];
#pragma unroll
    for (int kc = 0; kc < 4; kc++) ah[kc] = *(const f16x8*)(rb + rdo[kc]);
    const float* W1 = hW1 + (size_t)k * NH * NH;
    const int col = w * 16 + lr;
    f32x4 hacc;
    {
      const float b1 = hb1[k * NH + col];
      f32x4 binit = {b1, b1, b1, b1};
      hacc = binit;
    }
#pragma unroll
    for (int kc = 0; kc < 4; kc++) {
      const float* wrow = W1 + (size_t)col * NH + kc * 32 + kg * 8;
      const f32x4 w0 = *(const f32x4*)(wrow);
      const f32x4 w1 = *(const f32x4*)(wrow + 4);
      f16x8 wv;
      wv[0] = (f16)w0[0]; wv[1] = (f16)w0[1]; wv[2] = (f16)w0[2]; wv[3] = (f16)w0[3];
      wv[4] = (f16)w1[0]; wv[5] = (f16)w1[1]; wv[6] = (f16)w1[2]; wv[7] = (f16)w1[3];
      hacc = __builtin_amdgcn_mfma_f32_16x16x32_f16(ah[kc], wv, hacc, 0, 0, 0);
    }
#pragma unroll
    for (int jr = 0; jr < 4; jr++)
      hu[(kg * 4 + jr) * NH + col] = tanh_fast(hacc[jr]);
  }
  __syncthreads();
  if (w == 0) {
    const int b = l >> 2, part = l & 3;
    const float* W2 = hW2 + (size_t)k * NH;
    float s = 0.f;
#pragma unroll
    for (int j = 0; j < 32; j++)
      s += hu[b * NH + part * 32 + j] * W2[part * 32 + j];
    s += __shfl_xor(s, 1);
    s += __shfl_xor(s, 2);
    if (part == 0) out[k * NB + b0 + b] = s + hb2[k];
  }
}

// ------------------------------------------------------------- launch -------
extern "C" void kernel_launch(void* const* d_in, const int* in_sizes, int n_in,
                              void* d_out, int out_size, void* d_ws, size_t ws_size,
                              hipStream_t stream) {
  (void)in_sizes; (void)n_in; (void)out_size; (void)ws_size;
  const float* x = (const float*)d_in[0];
  const float* t0 = (const float*)d_in[1];
  const float* node = (const float*)d_in[2];
  const float* tau = (const float*)d_in[3];
  const float* endi = (const float*)d_in[4];
  const float* coords = (const float*)d_in[5];
  const float* Wx1 = (const float*)d_in[6];
  const float* Wx2 = (const float*)d_in[7];
  const float* bx2 = (const float*)d_in[8];
  const float* Wres = (const float*)d_in[9];
  const float* bres = (const float*)d_in[10];
  const float* Wnode = (const float*)d_in[11];
  const float* Wtau = (const float*)d_in[12];
  const float* btau = (const float*)d_in[13];
  const float* Wend1 = (const float*)d_in[14];
  const float* Wend2 = (const float*)d_in[15];
  const float* bend2 = (const float*)d_in[16];
  const float* Wcoord = (const float*)d_in[17];
  const float* Wih = (const float*)d_in[18];
  const float* Whh = (const float*)d_in[19];
  const float* bih = (const float*)d_in[20];
  const float* bhh = (const float*)d_in[21];
  const float* hW1 = (const float*)d_in[22];
  const float* hb1 = (const float*)d_in[23];
  const float* hW2 = (const float*)d_in[24];
  const float* hb2 = (const float*)d_in[25];

  char* ws = (char*)d_ws;
  f16* xh = (f16*)ws;      ws += (size_t)NB * NH * 2;
  f16* t0h = (f16*)ws;     ws += (size_t)NB * NH * 2;
  f16* endh = (f16*)ws;    ws += (size_t)NB * NH * 2;
  f16* tauh = (f16*)ws;    ws += (size_t)NB * NL * NH * 2;
  f16* nodeh = (f16*)ws;   ws += (size_t)NB * 2 * NL * NH * 2;
  f16* coordh = (f16*)ws;  ws += (size_t)NB * 2 * NL * NH * 2;
  f16* Wf = (f16*)ws;      ws += (size_t)NSF * 4096 * 2;
  f16* Wih16 = (f16*)ws;   ws += (size_t)7 * 512 * NH * 2;
  f16* Whh16 = (f16*)ws;   ws += (size_t)7 * 512 * NH * 2;
  float* bsum = (float*)ws;

  prep_kernel<<<1024, 256, 0, stream>>>(
      x, t0, tau, endi, coords, Wx1, Wx2, bx2, Wres, bres, Wnode, Wtau, btau,
      Wend1, Wend2, bend2, Wcoord, Wih, Whh, bih, bhh,
      xh, t0h, endh, tauh, coordh, Wf, Wih16, Whh16, bsum);
  node_gemm<<<256, 512, 0, stream>>>(node, Wf, nodeh);
  lstm_run<<<224, 512, 0, stream>>>(xh, t0h, endh, tauh, nodeh, coordh,
                                    Wih16, Whh16, bsum, hW1, hb1, hW2, hb2,
                                    (float*)d_out);
}

// Round 10
// 266.901 us; speedup vs baseline: 1.6311x; 1.1213x over previous
//
#include <hip/hip_runtime.h>
#include <hip/hip_fp16.h>

typedef _Float16 f16;
typedef _Float16 f16x8 __attribute__((ext_vector_type(8)));
typedef float f32x4 __attribute__((ext_vector_type(4)));

#define NB 512
#define NL 16
#define NK 10000
#define NH 128
#define NSF 316    // Wf 32-k sub-steps, zero-padded (79 * 4)
#define NT128 79   // K-steps of 128

__device__ __forceinline__ float fast_exp2(float x) {
#if __has_builtin(__builtin_amdgcn_exp2f)
  return __builtin_amdgcn_exp2f(x);
#else
  return exp2f(x);
#endif
}
__device__ __forceinline__ float fast_rcp(float x) {
#if __has_builtin(__builtin_amdgcn_rcpf)
  return __builtin_amdgcn_rcpf(x);
#else
  return 1.f / x;
#endif
}
__device__ __forceinline__ float sigf(float x) {
  return fast_rcp(1.f + fast_exp2(-1.44269504f * x));
}
__device__ __forceinline__ float tanh_fast(float x) {
  return 2.f * fast_rcp(1.f + fast_exp2(-2.88539008f * x)) - 1.f;
}

__device__ __forceinline__ void gload16(const void* g, void* l) {
  __builtin_amdgcn_global_load_lds(
      (const __attribute__((address_space(1))) unsigned int*)g,
      (__attribute__((address_space(3))) unsigned int*)l, 16, 0, 0);
}

// ---------------------------------------------------------------- prep ------
// Wf: B in MFMA-fragment order: [s][nt][lane][e] with lane=(kg*16+lr),
// value = Wnode[col=nt*16+lr][k=s*32+kg*8+e], zero-padded past K=10000.
__global__ void prep_kernel(
    const float* __restrict__ x, const float* __restrict__ t0,
    const float* __restrict__ tau, const float* __restrict__ endi,
    const float* __restrict__ coords,
    const float* __restrict__ Wx1, const float* __restrict__ Wx2,
    const float* __restrict__ bx2, const float* __restrict__ Wres,
    const float* __restrict__ bres, const float* __restrict__ Wnode,
    const float* __restrict__ Wtau, const float* __restrict__ btau,
    const float* __restrict__ Wend1, const float* __restrict__ Wend2,
    const float* __restrict__ bend2, const float* __restrict__ Wcoord,
    const float* __restrict__ Wih, const float* __restrict__ Whh,
    const float* __restrict__ bih, const float* __restrict__ bhh,
    f16* __restrict__ xh, f16* __restrict__ t0h, f16* __restrict__ endh,
    f16* __restrict__ tauh, f16* __restrict__ coordh, f16* __restrict__ Wf,
    f16* __restrict__ Wih16, f16* __restrict__ Whh16, float* __restrict__ bsum) {
  const int tid0 = blockIdx.x * blockDim.x + threadIdx.x;
  const int stride = gridDim.x * blockDim.x;

  const int nWf = NSF * 4096;       // 1,294,336 (incl. zero tail)
  const int nW = 7 * 512 * NH;      // 458,752
  const int nb = 7 * 512;
  const int nxh = NB * NH;          // 65,536
  const int ntau = NB * NL * NH;    // 1,048,576
  const int nco = NB * 2 * NL * NH; // 2,097,152

  for (int i = tid0; i < nWf; i += stride) {
    const int s = i >> 12, r = i & 4095;
    const int nt = r >> 9, l2 = r & 511;
    const int lane = l2 >> 3, e = l2 & 7;
    const int kg = lane >> 4, lr = lane & 15;
    const int col = nt * 16 + lr;
    const int k = s * 32 + kg * 8 + e;
    Wf[i] = (k < NK) ? (f16)Wnode[(size_t)col * NK + k] : (f16)0.f;
  }
  for (int i = tid0; i < nW; i += stride) {
    Wih16[i] = (f16)Wih[i];
    Whh16[i] = (f16)Whh[i];
  }
  for (int i = tid0; i < nb; i += stride) bsum[i] = bih[i] + bhh[i];
  for (int i = tid0; i < nxh; i += stride) {
    const int b = i >> 7, h = i & 127;
    const float s = x[2 * b] * Wx1[0] + x[2 * b + 1] * Wx1[1];
    xh[i] = (f16)tanhf(s * Wx2[h] + bx2[h]);
    t0h[i] = (f16)tanhf(t0[b] * Wres[h] + bres[h]);
    const float e = endi[2 * b] * Wend1[0] + endi[2 * b + 1] * Wend1[1];
    endh[i] = (f16)(e * Wend2[h] + bend2[h]);
  }
  for (int i = tid0; i < ntau; i += stride) {
    const int h = i & 127, bl = i >> 7;
    tauh[i] = (f16)tanhf(tau[bl] * Wtau[h] + btau[h]);
  }
  for (int i = tid0; i < nco; i += stride) {
    const int h = i & 127, br = i >> 7;
    coordh[i] = (f16)(coords[2 * br] * Wcoord[2 * h] +
                      coords[2 * br + 1] * Wcoord[2 * h + 1]);
  }
}

// ------------------------------------------------------------ node GEMM -----
// C(16384x128,f16) = A(16384x10000,f32) * W^T. Grid 256 wgs (1/CU), 512 thr.
// Tile = 64 rows x 128 k f32 (32 KB A), 4-deep LDS ring, 1-KB row bursts,
// counted vmcnt + raw barrier (R9 staging, unchanged). NEW: wave =
// (cp=w>>1 col-pair, kw=w&1 K-half): each wave covers ALL 64 rows (from LDS),
// 32 cols, 64 k -> B fragments are UNIQUE per wave (4 instr/tile vs 16),
// cutting per-wg vmem from 160 KB to 64 KB per tile. K-split partials
// reduced via an 8 x b128 LDS bounce at the epilogue.
__global__ __launch_bounds__(512, 2) void node_gemm(const float* __restrict__ A,
                                                    const f16* __restrict__ Wf,
                                                    f16* __restrict__ Cn) {
  __shared__ char lds[4][32768];
  const int tid = threadIdx.x;
  const int w = tid >> 6, l = tid & 63;
  const int lr = l & 15, kg = l >> 4;
  const int r0 = blockIdx.x * 64;
  char* lds0 = &lds[0][0];

  // ---- staging slots: slot i covers rows w*8+i*2+(l>>5), 16B per lane ----
  const char* ap[4];
  int bnd[4];
#pragma unroll
  for (int i = 0; i < 4; i++) {
    const int row = w * 8 + i * 2 + (l >> 5);
    const int bswz = ((l & 31) * 16) ^ ((row & 7) << 4);
    ap[i] = (const char*)A + (size_t)(r0 + row) * 40000 + bswz;
    bnd[i] = 39984 - bswz;  // clamp keeps 16B load in-bounds; Wf pad zeros it
  }

  // ---- compute assignment: all rows, cols [cp*32,+32), k-half kw ----
  const int cp = w >> 1;
  const int kw = w & 1;
  int rdoA[4][2][2];
#pragma unroll
  for (int rg = 0; rg < 4; rg++) {
    const int row = rg * 16 + lr;
    const int s = (row & 7) << 4;
#pragma unroll
    for (int ks = 0; ks < 2; ks++)
#pragma unroll
      for (int h = 0; h < 2; h++)
        rdoA[rg][ks][h] =
            row * 512 + ((kw * 256 + ks * 128 + kg * 32 + h * 16) ^ s);
  }

  f32x4 acc[4][2];
#pragma unroll
  for (int rg = 0; rg < 4; rg++)
#pragma unroll
    for (int j = 0; j < 2; j++) {
      f32x4 z = {0.f, 0.f, 0.f, 0.f};
      acc[rg][j] = z;
    }

  // stage tiles ta, ta+1: per row-slot the two 512-B chunks are issued
  // back-to-back -> 1 KB contiguous per row (DRAM page locality).
  auto burst = [&](int ta) {
    const int tb0 = ta * 512, tb1 = tb0 + 512;
    char* d0 = lds0 + (ta & 3) * 32768 + w * 4096;
    char* d1 = lds0 + ((ta + 1) & 3) * 32768 + w * 4096;
    const bool two = (ta + 1 < NT128);
#pragma unroll
    for (int i = 0; i < 4; i++) {
      gload16(ap[i] + (tb0 < bnd[i] ? tb0 : bnd[i]), d0 + i * 1024);
      if (two) gload16(ap[i] + (tb1 < bnd[i] ? tb1 : bnd[i]), d1 + i * 1024);
    }
  };

  // unique B share of this wave for tile t: 4 x b128
  auto loadB = [&](int t, f16x8 (&B)[2][2]) {
    const f16* bp = Wf + (size_t)(4 * t + 2 * kw) * 4096 + cp * 1024 + l * 8;
#pragma unroll
    for (int j = 0; j < 2; j++)
#pragma unroll
      for (int ks = 0; ks < 2; ks++)
        B[j][ks] = *(const f16x8*)(bp + (size_t)ks * 4096 + j * 512);
  };

  auto compute = [&](int t, const f16x8 (&B)[2][2]) {
    const char* cb = lds0 + (t & 3) * 32768;
#pragma unroll
    for (int ks = 0; ks < 2; ks++)
#pragma unroll
      for (int rg = 0; rg < 4; rg++) {
        const f32x4 a0 = *(const f32x4*)(cb + rdoA[rg][ks][0]);
        const f32x4 a1 = *(const f32x4*)(cb + rdoA[rg][ks][1]);
        f16x8 af;
        af[0] = (f16)a0[0]; af[1] = (f16)a0[1];
        af[2] = (f16)a0[2]; af[3] = (f16)a0[3];
        af[4] = (f16)a1[0]; af[5] = (f16)a1[1];
        af[6] = (f16)a1[2]; af[7] = (f16)a1[3];
#pragma unroll
        for (int j = 0; j < 2; j++)
          acc[rg][j] =
              __builtin_amdgcn_mfma_f32_16x16x32_f16(af, B[j][ks], acc[rg][j], 0, 0, 0);
      }
  };

  f16x8 BA[2][2], BB[2][2];

  // prologue: burst(0,1) = 8 loads (oldest in FIFO), then B(0) = 4 loads
  burst(0);
  loadB(0, BA);

  for (int e = 0; e < NT128 - 1; e += 2) {
    // retire burst(e,e+1) (and older B); keep loadB(e) in flight
    asm volatile("s_waitcnt vmcnt(4)" ::: "memory");
    __builtin_amdgcn_s_barrier();
    loadB(e + 1, BB);
    burst(e + 2);  // tile e+2 (and e+3 if valid)
    compute(e, BA);
    loadB(e + 2, BA);
    compute(e + 1, BB);
  }
  // tail tile 78 (B already in BA from the last group)
  asm volatile("s_waitcnt vmcnt(0)" ::: "memory");
  __builtin_amdgcn_s_barrier();
  compute(78, BA);

  // ---- K-split reduce (kw=1 partials -> LDS -> kw=0 adds & stores) ----
  if (kw == 1) {
#pragma unroll
    for (int rg = 0; rg < 4; rg++)
#pragma unroll
      for (int j = 0; j < 2; j++) {
        const int tl = (cp * 4 + rg) * 2 + j;
        *(f32x4*)(lds0 + tl * 1024 + l * 16) = acc[rg][j];
      }
  }
  __syncthreads();
  if (kw == 0) {
#pragma unroll
    for (int rg = 0; rg < 4; rg++)
#pragma unroll
      for (int j = 0; j < 2; j++) {
        const int tl = (cp * 4 + rg) * 2 + j;
        const f32x4 p = *(const f32x4*)(lds0 + tl * 1024 + l * 16);
        const f32x4 s = acc[rg][j] + p;
        f16* crow =
            Cn + (size_t)(r0 + rg * 16 + kg * 4) * NH + cp * 32 + j * 16 + lr;
#pragma unroll
        for (int jr = 0; jr < 4; jr++) crow[(size_t)jr * NH] = (f16)s[jr];
      }
  }
}

// --------------------------------------------------------------- LSTM -------
// grid: 7 k's x 32 batch-chunks of 16. One wg = 8 waves (512 thr); wave w
// owns hidden units [w*16, w*16+16) across all four gates (4 gate-tiles).
// Wih/Whh fragments in VGPRs (~128), x prefetched 1 step ahead. x-MFMAs run
// before h-MFMAs so the ds_read(h) latency hides under them.
__global__ __launch_bounds__(512, 2) void lstm_run(
    const f16* __restrict__ xh, const f16* __restrict__ t0h,
    const f16* __restrict__ endh, const f16* __restrict__ tauh,
    const f16* __restrict__ nodeh, const f16* __restrict__ coordh,
    const f16* __restrict__ Wih16, const f16* __restrict__ Whh16,
    const float* __restrict__ bsum, const float* __restrict__ hW1,
    const float* __restrict__ hb1, const float* __restrict__ hW2,
    const float* __restrict__ hb2, float* __restrict__ out) {
  __shared__ f16 hbuf[2][16 * NH];  // double-buffered h, XOR-swizzled bytes
  __shared__ float hu[16 * NH];

  const int k = blockIdx.x >> 5;
  const int b0 = (blockIdx.x & 31) << 4;
  const int w = threadIdx.x >> 6;
  const int l = threadIdx.x & 63;
  const int lr = l & 15, kg = l >> 4;

  int len;
  switch (k) {
    case 0: len = 83; break;
    case 1: len = 19; break;
    case 2: len = 32; break;
    case 3: len = 32; break;
    case 4: len = 51; break;
    case 5: len = 64; break;
    default: len = 51; break;
  }

  // per-step input fragment pointer (wave-uniform select logic)
  auto xptr = [&](int t) -> const f16* {
    const f16* cb; int bstr, idx;
    if (k == 2) { cb = nodeh; bstr = 32 * NH; idx = t; }
    else if (k == 3) { cb = coordh; bstr = 32 * NH; idx = t; }
    else if (k == 5) {
      const int q = t >> 2, r = t & 3;
      cb = (r == 0 || r == 2) ? nodeh : coordh;
      bstr = 32 * NH;
      idx = 2 * q + ((r >= 2) ? 1 : 0);
    } else {
      if (t == 0) { cb = xh; bstr = NH; idx = 0; }
      else if (t == 1) { cb = t0h; bstr = NH; idx = 0; }
      else if (t == len - 1) { cb = endh; bstr = NH; idx = 0; }
      else {
        const int u = t - 2;
        if (k == 0) {
          const int q = u / 5, r = u - 5 * q;
          if (r == 0) { cb = tauh; bstr = 16 * NH; idx = q; }
          else if (r == 1) { cb = nodeh; bstr = 32 * NH; idx = 2 * q; }
          else if (r == 2) { cb = coordh; bstr = 32 * NH; idx = 2 * q; }
          else if (r == 3) { cb = nodeh; bstr = 32 * NH; idx = 2 * q + 1; }
          else { cb = coordh; bstr = 32 * NH; idx = 2 * q + 1; }
        } else if (k == 1) { cb = tauh; bstr = 16 * NH; idx = u; }
        else if (k == 4) {
          const int q = u / 3, r = u - 3 * q;
          if (r == 0) { cb = tauh; bstr = 16 * NH; idx = q; }
          else { cb = nodeh; bstr = 32 * NH; idx = 2 * q + (r - 1); }
        } else {  // k == 6
          const int q = u / 3, r = u - 3 * q;
          if (r == 0) { cb = tauh; bstr = 16 * NH; idx = q; }
          else { cb = coordh; bstr = 32 * NH; idx = 2 * q + (r - 1); }
        }
      }
    }
    return cb + (size_t)(b0 + lr) * bstr + idx * NH + kg * 8;
  };

  // ---- load weight fragments into registers ----
  // wave w owns hidden cols [w*16, w*16+16); gate g's row block = g*128.
  f16x8 Wh[4][4], Wi[4][4];
  float bias[4];
  {
    const f16* whb = Whh16 + (size_t)k * 512 * NH;
    const f16* wib = Wih16 + (size_t)k * 512 * NH;
#pragma unroll
    for (int g = 0; g < 4; g++) {
      const int col = g * 128 + w * 16 + lr;
      bias[g] = bsum[k * 512 + col];
#pragma unroll
      for (int kc = 0; kc < 4; kc++) {
        Wh[kc][g] = *(const f16x8*)(whb + (size_t)col * NH + kc * 32 + kg * 8);
        Wi[kc][g] = *(const f16x8*)(wib + (size_t)col * NH + kc * 32 + kg * 8);
      }
    }
  }

  char* lds0 = (char*)&hbuf[0][0];
  // zero h buffer 0 (h0 = 0): 512 threads x 8 B = 4096 B
  *(unsigned long long*)(lds0 + threadIdx.x * 8) = 0ull;
  __syncthreads();

  float c[4] = {0, 0, 0, 0};

  // precomputed swizzled LDS byte offsets (constant across t)
  int rdo[4];
#pragma unroll
  for (int kc = 0; kc < 4; kc++) {
    const int colb = (kc * 32 + kg * 8) * 2;
    rdo[kc] = lr * 256 + (colb ^ ((lr & 7) << 4));
  }
  int wro[4];
#pragma unroll
  for (int jr = 0; jr < 4; jr++) {
    const int hrow = kg * 4 + jr;
    const int hcol = w * 16 + lr;
    wro[jr] = hrow * 256 + ((hcol * 2) ^ ((hrow & 7) << 4));
  }

  // prime x for t=0
  f16x8 axc[4];
  {
    const f16* xp = xptr(0);
#pragma unroll
    for (int kc = 0; kc < 4; kc++) axc[kc] = *(const f16x8*)(xp + kc * 32);
  }

  int cur = 0;
  for (int t = 0; t < len; t++) {
    char* rb = lds0 + cur * 4096;
    f16x8 ah[4];
#pragma unroll
    for (int kc = 0; kc < 4; kc++) ah[kc] = *(const f16x8*)(rb + rdo[kc]);

    // prefetch next-step x into registers (hidden under MFMA+gates+barrier)
    f16x8 axn[4];
    if (t + 1 < len) {
      const f16* xp = xptr(t + 1);
#pragma unroll
      for (int kc = 0; kc < 4; kc++) axn[kc] = *(const f16x8*)(xp + kc * 32);
    }

    f32x4 acc[4];
#pragma unroll
    for (int g = 0; g < 4; g++) {
      f32x4 binit = {bias[g], bias[g], bias[g], bias[g]};
      acc[g] = binit;
    }
    // x-part first (register operands ready) -> hides ds_read(h) latency
#pragma unroll
    for (int kc = 0; kc < 4; kc++)
#pragma unroll
      for (int g = 0; g < 4; g++)
        acc[g] = __builtin_amdgcn_mfma_f32_16x16x32_f16(axc[kc], Wi[kc][g], acc[g], 0, 0, 0);
#pragma unroll
    for (int kc = 0; kc < 4; kc++)
#pragma unroll
      for (int g = 0; g < 4; g++)
        acc[g] = __builtin_amdgcn_mfma_f32_16x16x32_f16(ah[kc], Wh[kc][g], acc[g], 0, 0, 0);

    // gates: acc[0]=i acc[1]=f acc[2]=g acc[3]=o
    char* wb = lds0 + (cur ^ 1) * 4096;
#pragma unroll
    for (int jr = 0; jr < 4; jr++) {
      const float iv = acc[0][jr];
      const float fv = acc[1][jr];
      const float gv = acc[2][jr];
      const float ov = acc[3][jr];
      const float cn = sigf(fv) * c[jr] + sigf(iv) * tanh_fast(gv);
      c[jr] = cn;
      const float hn = sigf(ov) * tanh_fast(cn);
      *(f16*)(wb + wro[jr]) = (f16)hn;
    }
    __syncthreads();
#pragma unroll
    for (int kc = 0; kc < 4; kc++) axc[kc] = axn[kc];
    cur ^= 1;
  }

  // ---- head: out = tanh(h @ W1^T + b1) @ W2^T + b2 ----
  {
    char* rb = lds0 + cur * 4096;
    f16x8 ah[4];
#pragma unroll
    for (int kc = 0; kc < 4; kc++) ah[kc] = *(const f16x8*)(rb + rdo[kc]);
    const float* W1 = hW1 + (size_t)k * NH * NH;
    const int col = w * 16 + lr;
    f32x4 hacc;
    {
      const float b1 = hb1[k * NH + col];
      f32x4 binit = {b1, b1, b1, b1};
      hacc = binit;
    }
#pragma unroll
    for (int kc = 0; kc < 4; kc++) {
      const float* wrow = W1 + (size_t)col * NH + kc * 32 + kg * 8;
      const f32x4 w0 = *(const f32x4*)(wrow);
      const f32x4 w1 = *(const f32x4*)(wrow + 4);
      f16x8 wv;
      wv[0] = (f16)w0[0]; wv[1] = (f16)w0[1]; wv[2] = (f16)w0[2]; wv[3] = (f16)w0[3];
      wv[4] = (f16)w1[0]; wv[5] = (f16)w1[1]; wv[6] = (f16)w1[2]; wv[7] = (f16)w1[3];
      hacc = __builtin_amdgcn_mfma_f32_16x16x32_f16(ah[kc], wv, hacc, 0, 0, 0);
    }
#pragma unroll
    for (int jr = 0; jr < 4; jr++)
      hu[(kg * 4 + jr) * NH + col] = tanh_fast(hacc[jr]);
  }
  __syncthreads();
  if (w == 0) {
    const int b = l >> 2, part = l & 3;
    const float* W2 = hW2 + (size_t)k * NH;
    float s = 0.f;
#pragma unroll
    for (int j = 0; j < 32; j++)
      s += hu[b * NH + part * 32 + j] * W2[part * 32 + j];
    s += __shfl_xor(s, 1);
    s += __shfl_xor(s, 2);
    if (part == 0) out[k * NB + b0 + b] = s + hb2[k];
  }
}

// ------------------------------------------------------------- launch -------
extern "C" void kernel_launch(void* const* d_in, const int* in_sizes, int n_in,
                              void* d_out, int out_size, void* d_ws, size_t ws_size,
                              hipStream_t stream) {
  (void)in_sizes; (void)n_in; (void)out_size; (void)ws_size;
  const float* x = (const float*)d_in[0];
  const float* t0 = (const float*)d_in[1];
  const float* node = (const float*)d_in[2];
  const float* tau = (const float*)d_in[3];
  const float* endi = (const float*)d_in[4];
  const float* coords = (const float*)d_in[5];
  const float* Wx1 = (const float*)d_in[6];
  const float* Wx2 = (const float*)d_in[7];
  const float* bx2 = (const float*)d_in[8];
  const float* Wres = (const float*)d_in[9];
  const float* bres = (const float*)d_in[10];
  const float* Wnode = (const float*)d_in[11];
  const float* Wtau = (const float*)d_in[12];
  const float* btau = (const float*)d_in[13];
  const float* Wend1 = (const float*)d_in[14];
  const float* Wend2 = (const float*)d_in[15];
  const float* bend2 = (const float*)d_in[16];
  const float* Wcoord = (const float*)d_in[17];
  const float* Wih = (const float*)d_in[18];
  const float* Whh = (const float*)d_in[19];
  const float* bih = (const float*)d_in[20];
  const float* bhh = (const float*)d_in[21];
  const float* hW1 = (const float*)d_in[22];
  const float* hb1 = (const float*)d_in[23];
  const float* hW2 = (const float*)d_in[24];
  const float* hb2 = (const float*)d_in[25];

  char* ws = (char*)d_ws;
  f16* xh = (f16*)ws;      ws += (size_t)NB * NH * 2;
  f16* t0h = (f16*)ws;     ws += (size_t)NB * NH * 2;
  f16* endh = (f16*)ws;    ws += (size_t)NB * NH * 2;
  f16* tauh = (f16*)ws;    ws += (size_t)NB * NL * NH * 2;
  f16* nodeh = (f16*)ws;   ws += (size_t)NB * 2 * NL * NH * 2;
  f16* coordh = (f16*)ws;  ws += (size_t)NB * 2 * NL * NH * 2;
  f16* Wf = (f16*)ws;      ws += (size_t)NSF * 4096 * 2;
  f16* Wih16 = (f16*)ws;   ws += (size_t)7 * 512 * NH * 2;
  f16* Whh16 = (f16*)ws;   ws += (size_t)7 * 512 * NH * 2;
  float* bsum = (float*)ws;

  prep_kernel<<<1024, 256, 0, stream>>>(
      x, t0, tau, endi, coords, Wx1, Wx2, bx2, Wres, bres, Wnode, Wtau, btau,
      Wend1, Wend2, bend2, Wcoord, Wih, Whh, bih, bhh,
      xh, t0h, endh, tauh, coordh, Wf, Wih16, Whh16, bsum);
  node_gemm<<<256, 512, 0, stream>>>(node, Wf, nodeh);
  lstm_run<<<224, 512, 0, stream>>>(xh, t0h, endh, tauh, nodeh, coordh,
                                    Wih16, Whh16, bsum, hW1, hb1, hW2, hb2,
                                    (float*)d_out);
}